// Round 5
// baseline (128.618 us; speedup 1.0000x reference)
//
#include <hip/hip_runtime.h>
#include <hip/hip_cooperative_groups.h>
#include <math.h>

namespace cg = cooperative_groups;

#define CL 4

constexpr float QMIN = 0.1f;
constexpr float EPS = 0.001f;   // EPS_LSE
constexpr float INV_BSE = 1.0f / 1.001f;

__device__ __forceinline__ float atanhsq(float b) {
  float a = atanhf(b * INV_BSE);
  return a * a;
}

// Single cooperative kernel: A) member stats  B) repulsion  C) finalize+scatter
__global__ __launch_bounds__(256) void fused_all(
    const float* __restrict__ beta, const float* __restrict__ coords,
    const int* __restrict__ asso, const int* __restrict__ M,
    const int* __restrict__ k_per_obj, const int* __restrict__ lengths,
    int Mmax, int N, int K, int B, int Nper, int Kper, int GPB, int SPLITB,
    float* __restrict__ k_sumV, float* __restrict__ k_cnt,
    float* __restrict__ k_bsk, float* __restrict__ k_sumpl,
    float* __restrict__ k_betapen, float* __restrict__ k_xc,  // [K][12]
    float* __restrict__ k_rep, float* __restrict__ noise,
    float* __restrict__ out) {
  cg::grid_group grid = cg::this_grid();
  const int tid = threadIdx.x;
  const int lane = tid & 63, w = tid >> 6;

  __shared__ float shV[4]; __shared__ int shI[4]; __shared__ float shM[4];
  __shared__ float s_xa[8]; __shared__ float s_scal[2];
  __shared__ float red5[5][4];
  __shared__ float redB[CL][4]; __shared__ float redn[4];
  __shared__ float red3[3][4];

  // ---------------- Phase A: per-cluster member stats ----------------
  for (int k = blockIdx.x; k < K; k += gridDim.x) {
    const int* Mrow = M + (long)k * Mmax;
    if (tid == 0) k_rep[k] = 0.f;
    if (k == 0 && tid < 16) noise[tid] = 0.f;

    // argmax of beta_scale (first-index tiebreak) + max beta
    float bestV = -1.f; int bestI = 0x7fffffff; float maxb = 0.f;
    for (int i = tid; i < Mmax; i += 256) {
      int idx = Mrow[i];
      if (idx >= 0) {
        float bb = beta[idx];
        float v = atanhsq(bb) + QMIN;
        if (v > bestV || (v == bestV && i < bestI)) { bestV = v; bestI = i; }
        maxb = fmaxf(maxb, bb);
      }
    }
    #pragma unroll
    for (int o = 32; o > 0; o >>= 1) {
      float v2 = __shfl_down(bestV, o, 64);
      int   i2 = __shfl_down(bestI, o, 64);
      float m2 = __shfl_down(maxb, o, 64);
      if (v2 > bestV || (v2 == bestV && i2 < bestI)) { bestV = v2; bestI = i2; }
      maxb = fmaxf(maxb, m2);
    }
    if (lane == 0) { shV[w] = bestV; shI[w] = bestI; shM[w] = maxb; }
    __syncthreads();
    if (tid == 0) {
      bestV = shV[0]; bestI = shI[0]; maxb = shM[0];
      for (int ww = 1; ww < 4; ++ww) {
        if (shV[ww] > bestV || (shV[ww] == bestV && shI[ww] < bestI)) { bestV = shV[ww]; bestI = shI[ww]; }
        maxb = fmaxf(maxb, shM[ww]);
      }
      int alpha = Mrow[bestI];
      const float4* ca = reinterpret_cast<const float4*>(coords) + (long)alpha * 2;
      float4 a0 = ca[0], a1 = ca[1];
      s_xa[0]=a0.x; s_xa[1]=a0.y; s_xa[2]=a0.z; s_xa[3]=a0.w;
      s_xa[4]=a1.x; s_xa[5]=a1.y; s_xa[6]=a1.z; s_xa[7]=a1.w;
      s_scal[0] = bestV; s_scal[1] = maxb;
    }
    __syncthreads();
    float xa[8];
    #pragma unroll
    for (int j = 0; j < 8; ++j) xa[j] = s_xa[j];
    maxb = s_scal[1];

    // member sums
    float sumV = 0.f, cnt = 0.f, sumpl = 0.f, sumbeta = 0.f, sumexp = 0.f;
    for (int i = tid; i < Mmax; i += 256) {
      int idx = Mrow[i];
      if (idx >= 0) {
        const float4* c4 = reinterpret_cast<const float4*>(coords) + (long)idx * 2;
        float4 p0 = c4[0], p1 = c4[1];
        float bb = beta[idx];
        float p = atanhsq(bb);
        float d0 = p0.x-xa[0], d1 = p0.y-xa[1], d2 = p0.z-xa[2], d3 = p0.w-xa[3];
        float d4 = p1.x-xa[4], d5 = p1.y-xa[5], d6 = p1.z-xa[6], d7 = p1.w-xa[7];
        float dsq = d0*d0+d1*d1+d2*d2+d3*d3+d4*d4+d5*d5+d6*d6+d7*d7;
        sumV   += dsq * (p + QMIN);
        cnt    += 1.f;
        sumpl  += p;
        sumbeta+= bb;
        sumexp += expf((bb - maxb) * (1.f / EPS));
      }
    }
    float vals[5] = {sumV, cnt, sumpl, sumbeta, sumexp};
    #pragma unroll
    for (int j = 0; j < 5; ++j) {
      float v = vals[j];
      #pragma unroll
      for (int o = 32; o > 0; o >>= 1) v += __shfl_down(v, o, 64);
      if (lane == 0) red5[j][w] = v;
    }
    __syncthreads();
    if (tid == 0) {
      float t[5];
      #pragma unroll
      for (int j = 0; j < 5; ++j) t[j] = red5[j][0] + red5[j][1] + red5[j][2] + red5[j][3];
      float bsk = s_scal[0];
      float cntT = t[1];
      float npad = (float)Mmax - cntT;               // zero-padded lse entries
      float sumexpT = t[4] + npad * expf(-maxb * (1.f / EPS));
      float lse = maxb * (1.f / EPS) + logf(sumexpT);
      float sb = fminf(fmaxf(t[3], 0.f), 1.f);
      k_betapen[k] = 1.f - EPS * lse + (1.f - sb);
      k_sumV[k]  = t[0] * bsk;                       // includes bs_k factor
      k_cnt[k]   = cntT;
      k_bsk[k]   = bsk;
      k_sumpl[k] = t[2];
      float xn2 = 0.f;
      #pragma unroll
      for (int j = 0; j < 8; ++j) xn2 += s_xa[j] * s_xa[j];
      float* dst = k_xc + (long)k * 12;
      #pragma unroll
      for (int j = 0; j < 8; ++j) dst[j] = s_xa[j];
      dst[8] = 0.5f * (xn2 - 1.f + 1e-6f);           // hit threshold offset
      dst[9] = xn2;
    }
    __syncthreads();
  }

  grid.sync();

  // ---------------- Phase B: repulsion tiles ----------------
  const int tiles = B * GPB * SPLITB;
  if ((int)blockIdx.x < tiles) {
    const int b  = blockIdx.x / (GPB * SPLITB);
    const int r  = blockIdx.x % (GPB * SPLITB);
    const int gi = r / SPLITB, s = r % SPLITB;
    const int c0 = gi * CL;                          // within-batch cluster base
    const int kg0 = b * Kper + c0;

    float xx[CL][8], ckv[CL], xnv[CL];
    #pragma unroll
    for (int c = 0; c < CL; ++c) {
      int kk = c0 + c;
      int kg = b * Kper + min(kk, Kper - 1);
      const float* src = k_xc + (long)kg * 12;
      #pragma unroll
      for (int j = 0; j < 8; ++j) xx[c][j] = src[j];
      ckv[c] = (kk < Kper) ? src[8] : 3.0e38f;       // dead cluster: never hits
      xnv[c] = src[9];
    }

    const int chunk = (Nper + SPLITB - 1) / SPLITB;
    const int lo = b * Nper + s * chunk;
    const int hi = min(b * Nper + Nper, lo + chunk);
    const bool donoise = (gi == 0);

    float srep[CL] = {0.f, 0.f, 0.f, 0.f};
    float snoise = 0.f;
    for (int n = lo + tid; n < hi; n += 256) {
      const float4* c4 = reinterpret_cast<const float4*>(coords) + (long)n * 2;
      float4 p0 = c4[0], p1 = c4[1];
      int a = asso[n];
      float pn2 = p0.x*p0.x + p0.y*p0.y + p0.z*p0.z + p0.w*p0.w
                + p1.x*p1.x + p1.y*p1.y + p1.z*p1.z + p1.w*p1.w;
      float hp = 0.5f * pn2;
      float bsn = -1.f;
      #pragma unroll
      for (int c = 0; c < CL; ++c) {
        float dot = p0.x*xx[c][0] + p0.y*xx[c][1] + p0.z*xx[c][2] + p0.w*xx[c][3]
                  + p1.x*xx[c][4] + p1.y*xx[c][5] + p1.z*xx[c][6] + p1.w*xx[c][7];
        if (dot - hp - ckv[c] > 0.f && a != kg0 + c) {   // dsq + 1e-6 < 1
          float t = fmaxf(pn2 + xnv[c] - 2.f * dot + 1e-6f, 0.f);
          if (bsn < 0.f) bsn = atanhsq(beta[n]) + QMIN;
          srep[c] += (1.f - sqrtf(t)) * bsn;
        }
      }
      if (donoise && a < 0) snoise += beta[n];
    }

    #pragma unroll
    for (int c = 0; c < CL; ++c) {
      float v = srep[c];
      #pragma unroll
      for (int o = 32; o > 0; o >>= 1) v += __shfl_down(v, o, 64);
      if (lane == 0) redB[c][w] = v;
    }
    #pragma unroll
    for (int o = 32; o > 0; o >>= 1) snoise += __shfl_down(snoise, o, 64);
    if (lane == 0) redn[w] = snoise;
    __syncthreads();
    if (tid == 0) {
      #pragma unroll
      for (int c = 0; c < CL; ++c) {
        float v = redB[c][0] + redB[c][1] + redB[c][2] + redB[c][3];
        if (c0 + c < Kper && v != 0.f) atomicAdd(&k_rep[kg0 + c], v);
      }
      if (donoise) {
        float v = redn[0] + redn[1] + redn[2] + redn[3];
        if (v != 0.f) atomicAdd(&noise[b], v);
      }
    }
  }

  grid.sync();

  // ---------------- Phase C: scatter + scalars ----------------
  const int stride = gridDim.x * 256;
  for (int n = blockIdx.x * 256 + tid; n < N; n += stride) {
    int a = asso[n];
    float op = 0.f, ol = 0.f;
    if (a >= 0) {
      float p = atanhsq(beta[n]);
      op = p / (k_sumpl[a] + 1e-12f);
      float cnt = k_cnt[a];
      ol = k_sumV[a] / (cnt + 1e-6f)
         + k_bsk[a] * k_rep[a] / ((float)Nper - cnt + 1e-6f);
    }
    out[3 + n] = op;
    out[3 + N + n] = ol;
  }
  if (blockIdx.x == 0) {
    float lv = 0.f, lrep = 0.f, lb = 0.f;
    for (int k = tid; k < K; k += 256) {
      float cnt = k_cnt[k];
      float LVk   = k_sumV[k] / (cnt + 1e-6f);
      float Lrepk = k_bsk[k] * k_rep[k] / ((float)Nper - cnt + 1e-6f);
      float invK  = 1.f / (float)k_per_obj[k];
      lv   += LVk * invK;
      lrep += Lrepk * invK;
      lb   += k_betapen[k] * invK;
    }
    float vals[3] = {lv, lrep, lb};
    #pragma unroll
    for (int j = 0; j < 3; ++j) {
      float v = vals[j];
      #pragma unroll
      for (int o = 32; o > 0; o >>= 1) v += __shfl_down(v, o, 64);
      if (lane == 0) red3[j][w] = v;
    }
    __syncthreads();
    if (tid == 0) {
      float noiseterm = 0.f;
      for (int bb = 0; bb < B; ++bb) noiseterm += noise[bb] / (float)lengths[bb];
      noiseterm /= (float)B;
      out[0] = red3[0][0] + red3[0][1] + red3[0][2] + red3[0][3];
      out[1] = red3[1][0] + red3[1][1] + red3[1][2] + red3[1][3];
      out[2] = red3[2][0] + red3[2][1] + red3[2][2] + red3[2][3] + noiseterm;
    }
  }
}

extern "C" void kernel_launch(void* const* d_in, const int* in_sizes, int n_in,
                              void* d_out, int out_size, void* d_ws, size_t ws_size,
                              hipStream_t stream) {
  const float* beta      = (const float*)d_in[0];
  const float* coords    = (const float*)d_in[1];
  const int*   asso      = (const int*)d_in[2];
  const int*   M         = (const int*)d_in[3];
  const int*   k_per_obj = (const int*)d_in[5];
  const int*   lengths   = (const int*)d_in[7];

  const int N    = in_sizes[0];
  const int K    = in_sizes[5];
  int Mmax = in_sizes[3] / K;
  int B    = in_sizes[7];
  int Nper = N / B;
  int Kper = K / B;

  float* ws        = (float*)d_ws;
  float* k_sumV    = ws;                   // K
  float* k_cnt     = k_sumV + K;           // K
  float* k_bsk     = k_cnt + K;            // K
  float* k_sumpl   = k_bsk + K;            // K
  float* k_betapen = k_sumpl + K;          // K
  float* k_xc      = k_betapen + K;        // K*12
  float* k_rep     = k_xc + (long)K * 12;  // K
  float* noise     = k_rep + K;            // 16

  float* out = (float*)d_out;

  const int G = 512;
  int GPB = (Kper + CL - 1) / CL;
  int SPLITB = G / (B * GPB); if (SPLITB < 1) SPLITB = 1;

  int N_ = N, K_ = K;
  void* args[] = {
    (void*)&beta, (void*)&coords, (void*)&asso, (void*)&M,
    (void*)&k_per_obj, (void*)&lengths,
    (void*)&Mmax, (void*)&N_, (void*)&K_, (void*)&B, (void*)&Nper,
    (void*)&Kper, (void*)&GPB, (void*)&SPLITB,
    (void*)&k_sumV, (void*)&k_cnt, (void*)&k_bsk, (void*)&k_sumpl,
    (void*)&k_betapen, (void*)&k_xc, (void*)&k_rep, (void*)&noise,
    (void*)&out
  };
  hipLaunchCooperativeKernel((void*)fused_all, dim3(G), dim3(256), args, 0, stream);
}

// Round 6
// 24.318 us; speedup vs baseline: 5.2890x; 5.2890x over previous
//
#include <hip/hip_runtime.h>
#include <math.h>

#define SPLIT 8
#define CL 4
#define MU 5   // fast-path covers Mmax <= MU*64 = 320 (here Mmax <= 300)

constexpr float QMIN = 0.1f;
constexpr float EPS = 0.001f;   // EPS_LSE
constexpr float INV_BSE = 1.0f / 1.001f;

__device__ __forceinline__ float atanhsq(float b) {
  float a = atanhf(b * INV_BSE);
  return a * a;
}

// ---- Kernel 1: member stats (1 wave/cluster, deep-ILP gathers) + repulsion
// grid = B * GPB * SPLIT, 256 threads. Wave w owns cluster c0+w's member
// phase; then all 4 waves stream chunk s of the batch against the group's
// CL condensation points with a register-resident dot-product hit test.
__global__ __launch_bounds__(256) void fused_cluster_rep(
    const float* __restrict__ beta, const float* __restrict__ coords,
    const int* __restrict__ asso, const int* __restrict__ M,
    int Mmax, int Nper, int Kper, int GPB,
    float* __restrict__ k_sumV, float* __restrict__ k_cnt,
    float* __restrict__ k_bsk, float* __restrict__ k_sumpl,
    float* __restrict__ k_betapen,
    float* __restrict__ rep_part, float* __restrict__ noise_part) {
  const int G = blockIdx.x / SPLIT, s = blockIdx.x % SPLIT;
  const int b = G / GPB, gi = G % GPB;
  const int c0 = b * Kper + gi * CL;
  const int ncl = min(CL, Kper - gi * CL);
  const int w = threadIdx.x >> 6, lane = threadIdx.x & 63;

  __shared__ float s_x[CL][12];     // x[8], ck, xn2
  __shared__ float redB[CL][4];
  __shared__ float redn[4];

  if (w < ncl) {
    const int k = c0 + w;
    const int* Mrow = M + (long)k * Mmax;

    // --- single-pass member load: all gathers in flight ---
    int   idxv[MU];
    float bbv[MU], plv[MU];
    float4 cav[MU], cbv[MU];
    #pragma unroll
    for (int u = 0; u < MU; ++u) {
      int i = lane + u * 64;
      idxv[u] = (i < Mmax) ? Mrow[i] : -1;
    }
    #pragma unroll
    for (int u = 0; u < MU; ++u) {
      int idx = idxv[u];
      if (idx >= 0) {
        bbv[u] = beta[idx];
        const float4* c4 = reinterpret_cast<const float4*>(coords) + (long)idx * 2;
        cav[u] = c4[0]; cbv[u] = c4[1];
      } else {
        bbv[u] = 0.f;
        cav[u] = make_float4(0.f,0.f,0.f,0.f);
        cbv[u] = make_float4(0.f,0.f,0.f,0.f);
      }
    }

    // --- phase 1: argmax of beta_scale (first-index tiebreak) + max beta ---
    float bestV = -1.f; int bestI = 0x7fffffff; float maxb = 0.f;
    #pragma unroll
    for (int u = 0; u < MU; ++u) {
      if (idxv[u] >= 0) {
        float p = atanhsq(bbv[u]);
        plv[u] = p;
        float v = p + QMIN;
        int i = lane + u * 64;
        if (v > bestV || (v == bestV && i < bestI)) { bestV = v; bestI = i; }
        maxb = fmaxf(maxb, bbv[u]);
      } else plv[u] = 0.f;
    }
    // generic tail (not taken for Mmax <= 320)
    for (int i = lane + MU * 64; i < Mmax; i += 64) {
      int idx = Mrow[i];
      if (idx >= 0) {
        float bb = beta[idx];
        float v = atanhsq(bb) + QMIN;
        if (v > bestV || (v == bestV && i < bestI)) { bestV = v; bestI = i; }
        maxb = fmaxf(maxb, bb);
      }
    }
    #pragma unroll
    for (int o = 1; o < 64; o <<= 1) {
      float v2 = __shfl_xor(bestV, o, 64);
      int   i2 = __shfl_xor(bestI, o, 64);
      float m2 = __shfl_xor(maxb, o, 64);
      if (v2 > bestV || (v2 == bestV && i2 < bestI)) { bestV = v2; bestI = i2; }
      maxb = fmaxf(maxb, m2);
    }
    int alpha = Mrow[bestI];                         // uniform addr: broadcast
    const float4* ca = reinterpret_cast<const float4*>(coords) + (long)alpha * 2;
    float4 a0 = ca[0], a1 = ca[1];
    float xa[8] = {a0.x, a0.y, a0.z, a0.w, a1.x, a1.y, a1.z, a1.w};

    // --- phase 2: member sums from registers ---
    float sumV = 0.f, cnt = 0.f, sumpl = 0.f, sumbeta = 0.f, sumexp = 0.f;
    #pragma unroll
    for (int u = 0; u < MU; ++u) {
      if (idxv[u] >= 0) {
        float d0 = cav[u].x-xa[0], d1 = cav[u].y-xa[1], d2 = cav[u].z-xa[2], d3 = cav[u].w-xa[3];
        float d4 = cbv[u].x-xa[4], d5 = cbv[u].y-xa[5], d6 = cbv[u].z-xa[6], d7 = cbv[u].w-xa[7];
        float dsq = d0*d0+d1*d1+d2*d2+d3*d3+d4*d4+d5*d5+d6*d6+d7*d7;
        sumV   += dsq * (plv[u] + QMIN);
        cnt    += 1.f;
        sumpl  += plv[u];
        sumbeta+= bbv[u];
        sumexp += expf((bbv[u] - maxb) * (1.f / EPS));
      }
    }
    for (int i = lane + MU * 64; i < Mmax; i += 64) {   // generic tail
      int idx = Mrow[i];
      if (idx >= 0) {
        const float4* c4 = reinterpret_cast<const float4*>(coords) + (long)idx * 2;
        float4 p0 = c4[0], p1 = c4[1];
        float bb = beta[idx];
        float p = atanhsq(bb);
        float d0 = p0.x-xa[0], d1 = p0.y-xa[1], d2 = p0.z-xa[2], d3 = p0.w-xa[3];
        float d4 = p1.x-xa[4], d5 = p1.y-xa[5], d6 = p1.z-xa[6], d7 = p1.w-xa[7];
        float dsq = d0*d0+d1*d1+d2*d2+d3*d3+d4*d4+d5*d5+d6*d6+d7*d7;
        sumV += dsq * (p + QMIN); cnt += 1.f; sumpl += p; sumbeta += bb;
        sumexp += expf((bb - maxb) * (1.f / EPS));
      }
    }
    float vals[5] = {sumV, cnt, sumpl, sumbeta, sumexp};
    #pragma unroll
    for (int j = 0; j < 5; ++j) {
      float v = vals[j];
      #pragma unroll
      for (int o = 32; o > 0; o >>= 1) v += __shfl_down(v, o, 64);
      vals[j] = v;
    }
    if (lane == 0) {
      float xn2 = 0.f;
      #pragma unroll
      for (int j = 0; j < 8; ++j) { s_x[w][j] = xa[j]; xn2 += xa[j] * xa[j]; }
      s_x[w][8] = 0.5f * (xn2 - 1.f + 1e-6f);        // dot-test threshold
      s_x[w][9] = xn2;
      if (s == 0) {
        float cntT = vals[1];
        float npad = (float)Mmax - cntT;             // zero-padded lse entries
        float sumexpT = vals[4] + npad * expf(-maxb * (1.f / EPS));
        float lse = maxb * (1.f / EPS) + logf(sumexpT);
        float sb = fminf(fmaxf(vals[3], 0.f), 1.f);
        k_betapen[k] = 1.f - EPS * lse + (1.f - sb);
        k_sumV[k]  = vals[0] * bestV;                // includes bs_k factor
        k_cnt[k]   = cntT;
        k_bsk[k]   = bestV;
        k_sumpl[k] = vals[2];
      }
    }
  } else if (w < CL) {
    if (lane == 0) {
      #pragma unroll
      for (int j = 0; j < 8; ++j) s_x[w][j] = 0.f;
      s_x[w][8] = 3.0e38f;                           // dead cluster: never hits
      s_x[w][9] = 0.f;
    }
  }
  __syncthreads();

  // --- phase 3: stream batch chunk against CL condensation points ---
  float xx[CL][8], ckv[CL], xnv[CL];
  #pragma unroll
  for (int c = 0; c < CL; ++c) {
    #pragma unroll
    for (int j = 0; j < 8; ++j) xx[c][j] = s_x[c][j];
    ckv[c] = s_x[c][8];
    xnv[c] = s_x[c][9];
  }

  const int chunk = (Nper + SPLIT - 1) / SPLIT;
  const int lo = b * Nper + s * chunk;
  const int hi = min(b * Nper + Nper, lo + chunk);
  const bool donoise = (gi == 0);

  float srep[CL] = {0.f, 0.f, 0.f, 0.f};
  float snoise = 0.f;
  for (int n = lo + threadIdx.x; n < hi; n += 256) {
    const float4* c4 = reinterpret_cast<const float4*>(coords) + (long)n * 2;
    float4 p0 = c4[0], p1 = c4[1];
    int a = asso[n];
    float pn2 = p0.x*p0.x + p0.y*p0.y + p0.z*p0.z + p0.w*p0.w
              + p1.x*p1.x + p1.y*p1.y + p1.z*p1.z + p1.w*p1.w;
    float hp = 0.5f * pn2;
    float bsn = -1.f;
    #pragma unroll
    for (int c = 0; c < CL; ++c) {
      float dot = p0.x*xx[c][0] + p0.y*xx[c][1] + p0.z*xx[c][2] + p0.w*xx[c][3]
                + p1.x*xx[c][4] + p1.y*xx[c][5] + p1.z*xx[c][6] + p1.w*xx[c][7];
      if (dot - hp - ckv[c] > 0.f && a != c0 + c) {  // dsq + 1e-6 < 1
        float t = fmaxf(pn2 + xnv[c] - 2.f * dot + 1e-6f, 0.f);
        if (bsn < 0.f) bsn = atanhsq(beta[n]) + QMIN;
        srep[c] += (1.f - sqrtf(t)) * bsn;
      }
    }
    if (donoise && a < 0) snoise += beta[n];
  }

  #pragma unroll
  for (int c = 0; c < CL; ++c) {
    float v = srep[c];
    #pragma unroll
    for (int o = 32; o > 0; o >>= 1) v += __shfl_down(v, o, 64);
    if (lane == 0) redB[c][w] = v;
  }
  #pragma unroll
  for (int o = 32; o > 0; o >>= 1) snoise += __shfl_down(snoise, o, 64);
  if (lane == 0) redn[w] = snoise;
  __syncthreads();
  if (threadIdx.x == 0) {
    for (int c = 0; c < ncl; ++c)
      rep_part[(c0 + c) * SPLIT + s] = redB[c][0] + redB[c][1] + redB[c][2] + redB[c][3];
    if (donoise) noise_part[b * SPLIT + s] = redn[0] + redn[1] + redn[2] + redn[3];
  }
}

// ---- Kernel 2: finalize scalars + scatter per-point outputs ---------------
__global__ __launch_bounds__(256) void out_kernel(
    const float* __restrict__ beta, const int* __restrict__ asso,
    const float* __restrict__ k_sumV, const float* __restrict__ k_cnt,
    const float* __restrict__ k_bsk, const float* __restrict__ k_sumpl,
    const float* __restrict__ k_betapen,
    const float* __restrict__ rep_part, const float* __restrict__ noise_part,
    const int* __restrict__ k_per_obj, const int* __restrict__ lengths,
    int K, int B, int Nper, int N, int nb, float* __restrict__ out) {
  if (blockIdx.x == (unsigned)nb) {
    float lv = 0.f, lrep = 0.f, lb = 0.f;
    for (int k = threadIdx.x; k < K; k += 256) {
      float cnt = k_cnt[k];
      float sr = 0.f;
      #pragma unroll
      for (int ss = 0; ss < SPLIT; ++ss) sr += rep_part[k * SPLIT + ss];
      float LVk   = k_sumV[k] / (cnt + 1e-6f);
      float Lrepk = k_bsk[k] * sr / ((float)Nper - cnt + 1e-6f);
      float invK  = 1.f / (float)k_per_obj[k];
      lv   += LVk * invK;
      lrep += Lrepk * invK;
      lb   += k_betapen[k] * invK;
    }
    const int lane = threadIdx.x & 63, w = threadIdx.x >> 6;
    __shared__ float red[3][4];
    float vals[3] = {lv, lrep, lb};
    #pragma unroll
    for (int j = 0; j < 3; ++j) {
      float v = vals[j];
      #pragma unroll
      for (int o = 32; o > 0; o >>= 1) v += __shfl_down(v, o, 64);
      if (lane == 0) red[j][w] = v;
    }
    __syncthreads();
    if (threadIdx.x == 0) {
      float noiseterm = 0.f;
      for (int bb = 0; bb < B; ++bb) {
        float npb = 0.f;
        for (int ss = 0; ss < SPLIT; ++ss) npb += noise_part[bb * SPLIT + ss];
        noiseterm += npb / (float)lengths[bb];
      }
      noiseterm /= (float)B;
      out[0] = red[0][0] + red[0][1] + red[0][2] + red[0][3];
      out[1] = red[1][0] + red[1][1] + red[1][2] + red[1][3];
      out[2] = red[2][0] + red[2][1] + red[2][2] + red[2][3] + noiseterm;
    }
  } else {
    int n = blockIdx.x * 256 + threadIdx.x;
    if (n < N) {
      int a = asso[n];
      float op = 0.f, ol = 0.f;
      if (a >= 0) {
        float p = atanhsq(beta[n]);
        op = p / (k_sumpl[a] + 1e-12f);
        float cnt = k_cnt[a];
        float sr = 0.f;
        #pragma unroll
        for (int ss = 0; ss < SPLIT; ++ss) sr += rep_part[a * SPLIT + ss];
        ol = k_sumV[a] / (cnt + 1e-6f)
           + k_bsk[a] * sr / ((float)Nper - cnt + 1e-6f);
      }
      out[3 + n] = op;
      out[3 + N + n] = ol;
    }
  }
}

extern "C" void kernel_launch(void* const* d_in, const int* in_sizes, int n_in,
                              void* d_out, int out_size, void* d_ws, size_t ws_size,
                              hipStream_t stream) {
  const float* beta      = (const float*)d_in[0];
  const float* coords    = (const float*)d_in[1];
  const int*   asso      = (const int*)d_in[2];
  const int*   M         = (const int*)d_in[3];
  const int*   k_per_obj = (const int*)d_in[5];
  const int*   lengths   = (const int*)d_in[7];

  const int N    = in_sizes[0];
  const int K    = in_sizes[5];
  const int Mmax = in_sizes[3] / K;
  const int B    = in_sizes[7];
  const int Nper = N / B;
  const int Kper = K / B;
  const int GPB  = (Kper + CL - 1) / CL;

  float* ws        = (float*)d_ws;
  float* k_sumV    = ws;                     // K
  float* k_cnt     = k_sumV + K;             // K
  float* k_bsk     = k_cnt + K;              // K
  float* k_sumpl   = k_bsk + K;              // K
  float* k_betapen = k_sumpl + K;            // K
  float* rep_part  = k_betapen + K;          // K*SPLIT
  float* noise_part= rep_part + K * SPLIT;   // B*SPLIT

  float* out = (float*)d_out;

  const int grid1 = B * GPB * SPLIT;
  fused_cluster_rep<<<grid1, 256, 0, stream>>>(
      beta, coords, asso, M, Mmax, Nper, Kper, GPB,
      k_sumV, k_cnt, k_bsk, k_sumpl, k_betapen, rep_part, noise_part);

  const int nb = (N + 255) / 256;
  out_kernel<<<nb + 1, 256, 0, stream>>>(
      beta, asso, k_sumV, k_cnt, k_bsk, k_sumpl, k_betapen,
      rep_part, noise_part, k_per_obj, lengths, K, B, Nper, N, nb, out);
}

// Round 7
// 24.304 us; speedup vs baseline: 5.2921x; 1.0006x over previous
//
#include <hip/hip_runtime.h>
#include <math.h>

#define SPLIT 8
#define CL 8
#define NW 8   // waves per block (512 threads)
#define MU 5   // fast-path covers Mmax <= MU*64 = 320 (here Mmax <= 300)

constexpr float QMIN = 0.1f;
constexpr float EPS = 0.001f;   // EPS_LSE
constexpr float INV_BSE = 1.0f / 1.001f;

__device__ __forceinline__ float atanhsq(float b) {
  float a = atanhf(b * INV_BSE);
  return a * a;
}

// ---- Kernel 1: member stats (1 wave/cluster, deep-ILP gathers) + repulsion
// grid = B * GPB * SPLIT, 512 threads (8 waves). Wave w owns cluster c0+w's
// member phase; then all waves stream chunk s of the batch against the
// group's CL=8 condensation points with a register dot-product hit test.
__global__ __launch_bounds__(512) void fused_cluster_rep(
    const float* __restrict__ beta, const float* __restrict__ coords,
    const int* __restrict__ asso, const int* __restrict__ M,
    int Mmax, int Nper, int Kper, int GPB,
    float* __restrict__ k_sumV, float* __restrict__ k_cnt,
    float* __restrict__ k_bsk, float* __restrict__ k_sumpl,
    float* __restrict__ k_betapen,
    float* __restrict__ rep_part, float* __restrict__ noise_part) {
  const int G = blockIdx.x / SPLIT, s = blockIdx.x % SPLIT;
  const int b = G / GPB, gi = G % GPB;
  const int c0 = b * Kper + gi * CL;                 // global cluster base
  const int ncl = min(CL, Kper - gi * CL);
  const int w = threadIdx.x >> 6, lane = threadIdx.x & 63;

  __shared__ float s_x[CL][12];     // x[8], ck, xn2
  __shared__ float redB[CL][NW];
  __shared__ float redn[NW];

  if (w < ncl) {
    const int k = c0 + w;
    const int* Mrow = M + (long)k * Mmax;

    // --- single-pass member load: all gathers in flight ---
    int   idxv[MU];
    float bbv[MU], plv[MU];
    float4 cav[MU], cbv[MU];
    #pragma unroll
    for (int u = 0; u < MU; ++u) {
      int i = lane + u * 64;
      idxv[u] = (i < Mmax) ? Mrow[i] : -1;
    }
    #pragma unroll
    for (int u = 0; u < MU; ++u) {
      int idx = idxv[u];
      if (idx >= 0) {
        bbv[u] = beta[idx];
        const float4* c4 = reinterpret_cast<const float4*>(coords) + (long)idx * 2;
        cav[u] = c4[0]; cbv[u] = c4[1];
      } else {
        bbv[u] = 0.f;
        cav[u] = make_float4(0.f,0.f,0.f,0.f);
        cbv[u] = make_float4(0.f,0.f,0.f,0.f);
      }
    }

    // --- phase 1: argmax of beta_scale (first-index tiebreak) + max beta ---
    float bestV = -1.f; int bestI = 0x7fffffff; float maxb = 0.f;
    #pragma unroll
    for (int u = 0; u < MU; ++u) {
      if (idxv[u] >= 0) {
        float p = atanhsq(bbv[u]);
        plv[u] = p;
        float v = p + QMIN;
        int i = lane + u * 64;
        if (v > bestV || (v == bestV && i < bestI)) { bestV = v; bestI = i; }
        maxb = fmaxf(maxb, bbv[u]);
      } else plv[u] = 0.f;
    }
    for (int i = lane + MU * 64; i < Mmax; i += 64) {   // generic tail
      int idx = Mrow[i];
      if (idx >= 0) {
        float bb = beta[idx];
        float v = atanhsq(bb) + QMIN;
        if (v > bestV || (v == bestV && i < bestI)) { bestV = v; bestI = i; }
        maxb = fmaxf(maxb, bb);
      }
    }
    #pragma unroll
    for (int o = 1; o < 64; o <<= 1) {
      float v2 = __shfl_xor(bestV, o, 64);
      int   i2 = __shfl_xor(bestI, o, 64);
      float m2 = __shfl_xor(maxb, o, 64);
      if (v2 > bestV || (v2 == bestV && i2 < bestI)) { bestV = v2; bestI = i2; }
      maxb = fmaxf(maxb, m2);
    }
    int alpha = Mrow[bestI];                         // uniform addr: broadcast
    const float4* ca = reinterpret_cast<const float4*>(coords) + (long)alpha * 2;
    float4 a0 = ca[0], a1 = ca[1];
    float xa[8] = {a0.x, a0.y, a0.z, a0.w, a1.x, a1.y, a1.z, a1.w};

    // --- phase 2: member sums from registers ---
    float sumV = 0.f, cnt = 0.f, sumpl = 0.f, sumbeta = 0.f, sumexp = 0.f;
    #pragma unroll
    for (int u = 0; u < MU; ++u) {
      if (idxv[u] >= 0) {
        float d0 = cav[u].x-xa[0], d1 = cav[u].y-xa[1], d2 = cav[u].z-xa[2], d3 = cav[u].w-xa[3];
        float d4 = cbv[u].x-xa[4], d5 = cbv[u].y-xa[5], d6 = cbv[u].z-xa[6], d7 = cbv[u].w-xa[7];
        float dsq = d0*d0+d1*d1+d2*d2+d3*d3+d4*d4+d5*d5+d6*d6+d7*d7;
        sumV   += dsq * (plv[u] + QMIN);
        cnt    += 1.f;
        sumpl  += plv[u];
        sumbeta+= bbv[u];
        sumexp += expf((bbv[u] - maxb) * (1.f / EPS));
      }
    }
    for (int i = lane + MU * 64; i < Mmax; i += 64) {   // generic tail
      int idx = Mrow[i];
      if (idx >= 0) {
        const float4* c4 = reinterpret_cast<const float4*>(coords) + (long)idx * 2;
        float4 p0 = c4[0], p1 = c4[1];
        float bb = beta[idx];
        float p = atanhsq(bb);
        float d0 = p0.x-xa[0], d1 = p0.y-xa[1], d2 = p0.z-xa[2], d3 = p0.w-xa[3];
        float d4 = p1.x-xa[4], d5 = p1.y-xa[5], d6 = p1.z-xa[6], d7 = p1.w-xa[7];
        float dsq = d0*d0+d1*d1+d2*d2+d3*d3+d4*d4+d5*d5+d6*d6+d7*d7;
        sumV += dsq * (p + QMIN); cnt += 1.f; sumpl += p; sumbeta += bb;
        sumexp += expf((bb - maxb) * (1.f / EPS));
      }
    }
    float vals[5] = {sumV, cnt, sumpl, sumbeta, sumexp};
    #pragma unroll
    for (int j = 0; j < 5; ++j) {
      float v = vals[j];
      #pragma unroll
      for (int o = 32; o > 0; o >>= 1) v += __shfl_down(v, o, 64);
      vals[j] = v;
    }
    if (lane == 0) {
      float xn2 = 0.f;
      #pragma unroll
      for (int j = 0; j < 8; ++j) { s_x[w][j] = xa[j]; xn2 += xa[j] * xa[j]; }
      s_x[w][8] = 0.5f * (xn2 - 1.f + 1e-6f);        // dot-test threshold
      s_x[w][9] = xn2;
      if (s == 0) {
        float cntT = vals[1];
        float npad = (float)Mmax - cntT;             // zero-padded lse entries
        float sumexpT = vals[4] + npad * expf(-maxb * (1.f / EPS));
        float lse = maxb * (1.f / EPS) + logf(sumexpT);
        float sb = fminf(fmaxf(vals[3], 0.f), 1.f);
        k_betapen[k] = 1.f - EPS * lse + (1.f - sb);
        k_sumV[k]  = vals[0] * bestV;                // includes bs_k factor
        k_cnt[k]   = cntT;
        k_bsk[k]   = bestV;
        k_sumpl[k] = vals[2];
      }
    }
  } else if (w < CL) {
    if (lane == 0) {
      #pragma unroll
      for (int j = 0; j < 8; ++j) s_x[w][j] = 0.f;
      s_x[w][8] = 3.0e38f;                           // dead cluster: never hits
      s_x[w][9] = 0.f;
    }
  }
  __syncthreads();

  // --- phase 3: stream batch chunk against CL condensation points ---
  float xx[CL][8], ckv[CL], xnv[CL];
  #pragma unroll
  for (int c = 0; c < CL; ++c) {
    #pragma unroll
    for (int j = 0; j < 8; ++j) xx[c][j] = s_x[c][j];
    ckv[c] = s_x[c][8];
    xnv[c] = s_x[c][9];
  }

  const int chunk = (Nper + SPLIT - 1) / SPLIT;
  const int lo = b * Nper + s * chunk;
  const int hi = min(b * Nper + Nper, lo + chunk);
  const bool donoise = (gi == 0);

  float srep[CL];
  #pragma unroll
  for (int c = 0; c < CL; ++c) srep[c] = 0.f;
  float snoise = 0.f;
  for (int n = lo + threadIdx.x; n < hi; n += 512) {
    const float4* c4 = reinterpret_cast<const float4*>(coords) + (long)n * 2;
    float4 p0 = c4[0], p1 = c4[1];
    int a = asso[n];
    float pn2 = p0.x*p0.x + p0.y*p0.y + p0.z*p0.z + p0.w*p0.w
              + p1.x*p1.x + p1.y*p1.y + p1.z*p1.z + p1.w*p1.w;
    float hp = 0.5f * pn2;
    float bsn = -1.f;
    #pragma unroll
    for (int c = 0; c < CL; ++c) {
      float dot = p0.x*xx[c][0] + p0.y*xx[c][1] + p0.z*xx[c][2] + p0.w*xx[c][3]
                + p1.x*xx[c][4] + p1.y*xx[c][5] + p1.z*xx[c][6] + p1.w*xx[c][7];
      if (dot - hp - ckv[c] > 0.f && a != c0 + c) {  // dsq + 1e-6 < 1
        float t = fmaxf(pn2 + xnv[c] - 2.f * dot + 1e-6f, 0.f);
        if (bsn < 0.f) bsn = atanhsq(beta[n]) + QMIN;
        srep[c] += (1.f - sqrtf(t)) * bsn;
      }
    }
    if (donoise && a < 0) snoise += beta[n];
  }

  #pragma unroll
  for (int c = 0; c < CL; ++c) {
    float v = srep[c];
    #pragma unroll
    for (int o = 32; o > 0; o >>= 1) v += __shfl_down(v, o, 64);
    if (lane == 0) redB[c][w] = v;
  }
  #pragma unroll
  for (int o = 32; o > 0; o >>= 1) snoise += __shfl_down(snoise, o, 64);
  if (lane == 0) redn[w] = snoise;
  __syncthreads();
  if (threadIdx.x == 0) {
    for (int c = 0; c < ncl; ++c) {
      float v = 0.f;
      #pragma unroll
      for (int ww = 0; ww < NW; ++ww) v += redB[c][ww];
      rep_part[(c0 + c) * SPLIT + s] = v;
    }
    if (donoise) {
      float v = 0.f;
      #pragma unroll
      for (int ww = 0; ww < NW; ++ww) v += redn[ww];
      noise_part[b * SPLIT + s] = v;
    }
  }
}

// ---- Kernel 2: finalize scalars + scatter per-point outputs ---------------
__global__ __launch_bounds__(256) void out_kernel(
    const float* __restrict__ beta, const int* __restrict__ asso,
    const float* __restrict__ k_sumV, const float* __restrict__ k_cnt,
    const float* __restrict__ k_bsk, const float* __restrict__ k_sumpl,
    const float* __restrict__ k_betapen,
    const float* __restrict__ rep_part, const float* __restrict__ noise_part,
    const int* __restrict__ k_per_obj, const int* __restrict__ lengths,
    int K, int B, int Nper, int N, int nb, float* __restrict__ out) {
  if (blockIdx.x == (unsigned)nb) {
    float lv = 0.f, lrep = 0.f, lb = 0.f;
    for (int k = threadIdx.x; k < K; k += 256) {
      float cnt = k_cnt[k];
      float sr = 0.f;
      #pragma unroll
      for (int ss = 0; ss < SPLIT; ++ss) sr += rep_part[k * SPLIT + ss];
      float LVk   = k_sumV[k] / (cnt + 1e-6f);
      float Lrepk = k_bsk[k] * sr / ((float)Nper - cnt + 1e-6f);
      float invK  = 1.f / (float)k_per_obj[k];
      lv   += LVk * invK;
      lrep += Lrepk * invK;
      lb   += k_betapen[k] * invK;
    }
    const int lane = threadIdx.x & 63, w = threadIdx.x >> 6;
    __shared__ float red[3][4];
    float vals[3] = {lv, lrep, lb};
    #pragma unroll
    for (int j = 0; j < 3; ++j) {
      float v = vals[j];
      #pragma unroll
      for (int o = 32; o > 0; o >>= 1) v += __shfl_down(v, o, 64);
      if (lane == 0) red[j][w] = v;
    }
    __syncthreads();
    if (threadIdx.x == 0) {
      float noiseterm = 0.f;
      for (int bb = 0; bb < B; ++bb) {
        float npb = 0.f;
        for (int ss = 0; ss < SPLIT; ++ss) npb += noise_part[bb * SPLIT + ss];
        noiseterm += npb / (float)lengths[bb];
      }
      noiseterm /= (float)B;
      out[0] = red[0][0] + red[0][1] + red[0][2] + red[0][3];
      out[1] = red[1][0] + red[1][1] + red[1][2] + red[1][3];
      out[2] = red[2][0] + red[2][1] + red[2][2] + red[2][3] + noiseterm;
    }
  } else {
    int n = blockIdx.x * 256 + threadIdx.x;
    if (n < N) {
      int a = asso[n];
      float op = 0.f, ol = 0.f;
      if (a >= 0) {
        float p = atanhsq(beta[n]);
        op = p / (k_sumpl[a] + 1e-12f);
        float cnt = k_cnt[a];
        float sr = 0.f;
        #pragma unroll
        for (int ss = 0; ss < SPLIT; ++ss) sr += rep_part[a * SPLIT + ss];
        ol = k_sumV[a] / (cnt + 1e-6f)
           + k_bsk[a] * sr / ((float)Nper - cnt + 1e-6f);
      }
      out[3 + n] = op;
      out[3 + N + n] = ol;
    }
  }
}

extern "C" void kernel_launch(void* const* d_in, const int* in_sizes, int n_in,
                              void* d_out, int out_size, void* d_ws, size_t ws_size,
                              hipStream_t stream) {
  const float* beta      = (const float*)d_in[0];
  const float* coords    = (const float*)d_in[1];
  const int*   asso      = (const int*)d_in[2];
  const int*   M         = (const int*)d_in[3];
  const int*   k_per_obj = (const int*)d_in[5];
  const int*   lengths   = (const int*)d_in[7];

  const int N    = in_sizes[0];
  const int K    = in_sizes[5];
  const int Mmax = in_sizes[3] / K;
  const int B    = in_sizes[7];
  const int Nper = N / B;
  const int Kper = K / B;
  const int GPB  = (Kper + CL - 1) / CL;

  float* ws        = (float*)d_ws;
  float* k_sumV    = ws;                     // K
  float* k_cnt     = k_sumV + K;             // K
  float* k_bsk     = k_cnt + K;              // K
  float* k_sumpl   = k_bsk + K;              // K
  float* k_betapen = k_sumpl + K;            // K
  float* rep_part  = k_betapen + K;          // K*SPLIT
  float* noise_part= rep_part + K * SPLIT;   // B*SPLIT

  float* out = (float*)d_out;

  const int grid1 = B * GPB * SPLIT;
  fused_cluster_rep<<<grid1, 512, 0, stream>>>(
      beta, coords, asso, M, Mmax, Nper, Kper, GPB,
      k_sumV, k_cnt, k_bsk, k_sumpl, k_betapen, rep_part, noise_part);

  const int nb = (N + 255) / 256;
  out_kernel<<<nb + 1, 256, 0, stream>>>(
      beta, asso, k_sumV, k_cnt, k_bsk, k_sumpl, k_betapen,
      rep_part, noise_part, k_per_obj, lengths, K, B, Nper, N, nb, out);
}